// Round 10
// baseline (5831.454 us; speedup 1.0000x reference)
//
#include <hip/hip_runtime.h>
#include <stdint.h>

#define T_STEPS 101
#define ROWS 1600
#define NTHR 512
#define NBLK 512            /* 2 batches per block, 1024 batches total */
#define NZ1 40
#define NZ2 50
#define OFF2 (NZ1 * ROWS)              /* 64000  */
#define OFF3 (OFF2 + NZ2 * ROWS)       /* 144000 */
#define NZTOT (OFF3 + NZ2 * ROWS)      /* 224000 entries (uint2 = 1.79 MB) */

__device__ __forceinline__ float sigmoidf(float v) { return 1.0f / (1.0f + expf(-v)); }

// ---------------------------------------------------------------------------
// Prep: fixed-length CSR, one uint2 {w_bits, byte_off} per nonzero.
// SoA ent[j*1600 + r] for lane-coalesced dwordx2 streams. byte_off = col*8
// indexes a float2 k-table (works for both the 320-entry L1 table and the
// 400-entry L2/3 table). Padding entries {0,0}: fmaf(0, k[0], a) == a.
// Ascending col order == round-1's verified op order.
// ---------------------------------------------------------------------------
__global__ void prep_kernel(const float* __restrict__ W1, const float* __restrict__ W2,
                            const float* __restrict__ W3, uint2* __restrict__ ent) {
  int gid = blockIdx.x * blockDim.x + threadIdx.x;
  if (gid >= 3 * ROWS) return;
  int l = gid / ROWS, r = gid - l * ROWS;
  const float* W; int in_f, knz, off;
  if (l == 0)      { W = W1; in_f = 320; knz = NZ1; off = 0;    }
  else if (l == 1) { W = W2; in_f = 400; knz = NZ2; off = OFF2; }
  else             { W = W3; in_f = 400; knz = NZ2; off = OFF3; }
  uint2* e = ent + off;
  int cnt = 0;
  for (int col = 0; col < in_f; ++col) {
    float w = W[(size_t)r * in_f + col];
    if (w != 0.0f && cnt < knz) {
      e[cnt * ROWS + r] = make_uint2(__float_as_uint(w), (uint32_t)(col * 8));
      ++cnt;
    }
  }
  for (; cnt < knz; ++cnt) e[cnt * ROWS + r] = make_uint2(0u, 0u);
}

// ---------------------------------------------------------------------------
// One row-slot, 2 batch lanes. Unified gather: one dwordx2 {w, off} + one
// ds_read_b64 float2 + 2 fma per nonzero. Same j order / fma forms as the
// verified round-9 kernel (spike floats are exactly 0.0/1.0 -> bitwise
// identical to the u8-cvt path). Unroll 10 = proven spill-free window.
// ---------------------------------------------------------------------------
template<int KNZ>
__device__ __forceinline__ void slot_compute(
    int tid, int r, const uint2* __restrict__ ent, const uint8_t* __restrict__ ktab,
    float bt, float bias, float al,
    float (&dreg)[2], uint8_t (*s_l)[2], float (*mem_l)[2])
{
  float a0 = bias, a1 = bias;
  const uint2* ep = ent + r;
#pragma unroll 10
  for (int j = 0; j < KNZ; ++j) {
    const uint2 e = ep[(size_t)j * ROWS];
    const float w = __uint_as_float(e.x);
    const float2 kv = *reinterpret_cast<const float2*>(ktab + e.y);
    a0 = fmaf(w, kv.x, a0);
    a1 = fmaf(w, kv.y, a1);
  }
  // d = beta*d + (1-beta)*ff
  const float ob = 1.0f - bt;
  float d0 = fmaf(bt, dreg[0], ob * a0);
  float d1 = fmaf(bt, dreg[1], ob * a1);
  dreg[0] = d0; dreg[1] = d1;
  // branch sum over the neuron's 8 rows (8 consecutive, 8-aligned lanes)
  d0 += __shfl_xor(d0, 1); d0 += __shfl_xor(d0, 2); d0 += __shfl_xor(d0, 4);
  d1 += __shfl_xor(d1, 1); d1 += __shfl_xor(d1, 2); d1 += __shfl_xor(d1, 4);
  if ((tid & 7) == 0) {
    const int n = r >> 3;
    const float oa = 1.0f - al;
    float2 mv = *reinterpret_cast<float2*>(&mem_l[n][0]);
    const uint32_t so = *reinterpret_cast<uint16_t*>(&s_l[n][0]);
    // mem = (mem - vth*spike)*alpha + (1-alpha)*sum(d)
    const float m0 = fmaf(mv.x - (float)(so & 0xffu), al, oa * d0);
    const float m1 = fmaf(mv.y - (float)(so >> 8),    al, oa * d1);
    *reinterpret_cast<float2*>(&mem_l[n][0]) = make_float2(m0, m1);
    const uint16_t sn = (uint16_t)((m0 > 1.0f ? 1u : 0u) | (m1 > 1.0f ? 0x100u : 0u));
    *reinterpret_cast<uint16_t*>(&s_l[n][0]) = sn;
  }
}

// ---------------------------------------------------------------------------
// Main kernel: 512 blocks x 512 threads, 2 batches/block (round-9 structure,
// which measured VGPR=112 / zero spill / VALUBusy 39%). This round halves
// VMEM instructions (fused uint2 entries) and removes the u8->f32 cvt chain
// (float2 spike tables) -- ~30% fewer dynamic instructions.
// ---------------------------------------------------------------------------
__global__ void __launch_bounds__(NTHR, 2)
snn_main(const float* __restrict__ x,
         const float* __restrict__ b1, const float* __restrict__ tm1, const float* __restrict__ tn1,
         const float* __restrict__ b2, const float* __restrict__ tm2, const float* __restrict__ tn2,
         const float* __restrict__ b3, const float* __restrict__ tm3, const float* __restrict__ tn3,
         const float* __restrict__ W4, const float* __restrict__ b4, const float* __restrict__ tm4,
         const uint2* __restrict__ ent,
         float* __restrict__ out)
{
  __shared__ __align__(16) float2  k1f[320];          // L1 table: x | s1 (f32 pairs)
  __shared__ __align__(16) float2  k23f[400];         // L2/3 table: spikes as f32 pairs
  __shared__ __align__(4)  uint8_t s_lds[3][200][2];  // spike state (exact 0/1)
  __shared__ __align__(16) float   mem_lds[3][200][2];
  __shared__ float w4_lds[12][201];

  const int tid = threadIdx.x;
  const int bg  = blockIdx.x;          // batches bg*2, bg*2+1

  for (int idx = tid; idx < 300; idx += NTHR) {
    reinterpret_cast<uint32_t*>(&s_lds[0][0][0])[idx] = 0u;
    reinterpret_cast<float4*>(&mem_lds[0][0][0])[idx] = make_float4(0.f, 0.f, 0.f, 0.f);
  }
  for (int idx = tid; idx < 12 * 200; idx += NTHR)
    w4_lds[idx / 200][idx % 200] = W4[idx];

  float d[3][4][2];
#pragma unroll
  for (int l = 0; l < 3; ++l)
#pragma unroll
    for (int i = 0; i < 4; ++i)
#pragma unroll
      for (int b = 0; b < 2; ++b) d[l][i][b] = 0.0f;

  float beta[3][4], bia[3][4], alpha[3][4];
#pragma unroll
  for (int i = 0; i < 4; ++i) {
    const int r = (i < 3) ? (tid + NTHR * i) : (1536 + (tid & 63));
    const int n = r >> 3;
    beta[0][i] = sigmoidf(tn1[r]); bia[0][i] = b1[r]; alpha[0][i] = sigmoidf(tm1[n]);
    beta[1][i] = sigmoidf(tn2[r]); bia[1][i] = b2[r]; alpha[1][i] = sigmoidf(tm2[n]);
    beta[2][i] = sigmoidf(tn3[r]); bia[2][i] = b3[r]; alpha[2][i] = sigmoidf(tm3[n]);
  }

  float m4_reg = 0.0f, m4_acc = 0.0f, a4 = 0.0f, b4r = 0.0f;
  if (tid < 24) { const int o = tid >> 1; a4 = sigmoidf(tm4[o]); b4r = b4[o]; }
  __syncthreads();

  const uint8_t* k1b = reinterpret_cast<const uint8_t*>(&k1f[0]);
  const uint8_t* k2b = reinterpret_cast<const uint8_t*>(&k23f[0]);

  for (int t = 0; t < T_STEPS; ++t) {
    // ---- build k1 = [x_t | s1(old)] -----------------------------------
    if (tid < 240) {
      const int bat = tid / 120, cf = tid - bat * 120;
      const int c = cf / 40, f = cf - c * 40;
      const int b = bg * 2 + bat;
      reinterpret_cast<float*>(&k1f[cf])[bat] =
          x[(((size_t)b * 3 + c) * T_STEPS + t) * 40 + f];
    }
    if (tid < 200) {
      const uint32_t so = *reinterpret_cast<const uint16_t*>(&s_lds[0][tid][0]);
      k1f[120 + tid] = make_float2((float)(so & 0xffu), (float)(so >> 8));
    }
    __syncthreads();
    slot_compute<NZ1>(tid, tid,        ent, k1b, beta[0][0], bia[0][0], alpha[0][0],
                      d[0][0], s_lds[0], mem_lds[0]);
    slot_compute<NZ1>(tid, tid + 512,  ent, k1b, beta[0][1], bia[0][1], alpha[0][1],
                      d[0][1], s_lds[0], mem_lds[0]);
    slot_compute<NZ1>(tid, tid + 1024, ent, k1b, beta[0][2], bia[0][2], alpha[0][2],
                      d[0][2], s_lds[0], mem_lds[0]);
    if (tid < 64)
      slot_compute<NZ1>(tid, 1536 + tid, ent, k1b, beta[0][3], bia[0][3], alpha[0][3],
                        d[0][3], s_lds[0], mem_lds[0]);
    __syncthreads();
    // ---- build k2 = [s1(new) | s2(old)] as float2 ---------------------
    if (tid < 200) {
      const uint32_t so = *reinterpret_cast<const uint16_t*>(&s_lds[0][tid][0]);
      k23f[tid] = make_float2((float)(so & 0xffu), (float)(so >> 8));
    } else if (tid < 400) {
      const uint32_t so = *reinterpret_cast<const uint16_t*>(&s_lds[1][tid - 200][0]);
      k23f[tid] = make_float2((float)(so & 0xffu), (float)(so >> 8));
    }
    __syncthreads();
    slot_compute<NZ2>(tid, tid,        ent + OFF2, k2b, beta[1][0], bia[1][0], alpha[1][0],
                      d[1][0], s_lds[1], mem_lds[1]);
    slot_compute<NZ2>(tid, tid + 512,  ent + OFF2, k2b, beta[1][1], bia[1][1], alpha[1][1],
                      d[1][1], s_lds[1], mem_lds[1]);
    slot_compute<NZ2>(tid, tid + 1024, ent + OFF2, k2b, beta[1][2], bia[1][2], alpha[1][2],
                      d[1][2], s_lds[1], mem_lds[1]);
    if (tid < 64)
      slot_compute<NZ2>(tid, 1536 + tid, ent + OFF2, k2b, beta[1][3], bia[1][3], alpha[1][3],
                        d[1][3], s_lds[1], mem_lds[1]);
    __syncthreads();
    // ---- build k3 = [s2(new) | s3(old)] as float2 ---------------------
    if (tid < 200) {
      const uint32_t so = *reinterpret_cast<const uint16_t*>(&s_lds[1][tid][0]);
      k23f[tid] = make_float2((float)(so & 0xffu), (float)(so >> 8));
    } else if (tid < 400) {
      const uint32_t so = *reinterpret_cast<const uint16_t*>(&s_lds[2][tid - 200][0]);
      k23f[tid] = make_float2((float)(so & 0xffu), (float)(so >> 8));
    }
    __syncthreads();
    slot_compute<NZ2>(tid, tid,        ent + OFF3, k2b, beta[2][0], bia[2][0], alpha[2][0],
                      d[2][0], s_lds[2], mem_lds[2]);
    slot_compute<NZ2>(tid, tid + 512,  ent + OFF3, k2b, beta[2][1], bia[2][1], alpha[2][1],
                      d[2][1], s_lds[2], mem_lds[2]);
    slot_compute<NZ2>(tid, tid + 1024, ent + OFF3, k2b, beta[2][2], bia[2][2], alpha[2][2],
                      d[2][2], s_lds[2], mem_lds[2]);
    if (tid < 64)
      slot_compute<NZ2>(tid, 1536 + tid, ent + OFF3, k2b, beta[2][3], bia[2][3], alpha[2][3],
                        d[2][3], s_lds[2], mem_lds[2]);
    __syncthreads();
    // ---- leaky readout (wave 0; overlaps next step's staging) ---------
    if (tid < 24) {
      const int o = tid >> 1, bat = tid & 1;
      float dot = b4r;
#pragma unroll 8
      for (int n = 0; n < 200; ++n)
        dot = fmaf(w4_lds[o][n], (float)s_lds[2][n][bat], dot);
      m4_reg = a4 * m4_reg + (1.0f - a4) * dot;
      m4_acc += m4_reg;
    }
    // no trailing barrier: stage-k1(t+1) touches only k1f / s_lds[0];
    // readout touches only s_lds[2] / w4_lds.
  }

  // ---- log_softmax(acc / T) -------------------------------------------
  __syncthreads();
  if (tid < 24) {
    const int o = tid >> 1, bat = tid & 1;
    reinterpret_cast<float*>(&k1f[o])[bat] = m4_acc * (1.0f / (float)T_STEPS);
  }
  __syncthreads();
  if (tid < 2) {
    const int bat = tid;
    float v[12], mx = -1e30f;
#pragma unroll
    for (int o = 0; o < 12; ++o) {
      v[o] = reinterpret_cast<float*>(&k1f[o])[bat];
      mx = fmaxf(mx, v[o]);
    }
    float s = 0.0f;
#pragma unroll
    for (int o = 0; o < 12; ++o) s += expf(v[o] - mx);
    const float ls = logf(s);
#pragma unroll
    for (int o = 0; o < 12; ++o)
      out[((size_t)(bg * 2 + bat)) * 12 + o] = v[o] - mx - ls;
  }
}

// ---------------------------------------------------------------------------
extern "C" void kernel_launch(void* const* d_in, const int* in_sizes, int n_in,
                              void* d_out, int out_size, void* d_ws, size_t ws_size,
                              hipStream_t stream) {
  (void)in_sizes; (void)n_in; (void)out_size; (void)ws_size;
  const float* x   = (const float*)d_in[0];
  const float* W1  = (const float*)d_in[1];
  const float* b1  = (const float*)d_in[2];
  const float* tm1 = (const float*)d_in[3];
  const float* tn1 = (const float*)d_in[4];
  const float* W2  = (const float*)d_in[5];
  const float* b2  = (const float*)d_in[6];
  const float* tm2 = (const float*)d_in[7];
  const float* tn2 = (const float*)d_in[8];
  const float* W3  = (const float*)d_in[9];
  const float* b3  = (const float*)d_in[10];
  const float* tm3 = (const float*)d_in[11];
  const float* tn3 = (const float*)d_in[12];
  const float* W4  = (const float*)d_in[13];
  const float* b4  = (const float*)d_in[14];
  const float* tm4 = (const float*)d_in[15];

  uint2* ent = (uint2*)d_ws;                       // 224000 uint2 = 1.79 MB

  prep_kernel<<<dim3(19), dim3(256), 0, stream>>>(W1, W2, W3, ent);
  snn_main<<<dim3(NBLK), dim3(NTHR), 0, stream>>>(
      x, b1, tm1, tn1, b2, tm2, tn2, b3, tm3, tn3, W4, b4, tm4,
      ent, (float*)d_out);
}